// Round 1
// baseline (626.009 us; speedup 1.0000x reference)
//
#include <hip/hip_runtime.h>

// Problem constants (from reference)
constexpr int SRC = 2000000;      // SRC_SIZE
constexpr int NN  = 4000000;      // NUM_NEURONS
// NUM_WEIGHTS = 8

// Pass 1: build T[i] = values_a[idx_a[i]] for i < SRC, values_b[idx_b[i-SRC]] otherwise.
// SRC is divisible by 4, so each float4 chunk is entirely in one half.
__global__ __launch_bounds__(256) void build_table_kernel(
    const float* __restrict__ va, const float* __restrict__ vb,
    const int*   __restrict__ ia, const int*   __restrict__ ib,
    float* __restrict__ table)
{
    const int total4 = (2 * SRC) / 4;  // 1,000,000 float4 chunks
    const int half4  = SRC / 4;        // 500,000
    const int stride = gridDim.x * blockDim.x;
    for (int i = blockIdx.x * blockDim.x + threadIdx.x; i < total4; i += stride) {
        float4 r;
        if (i < half4) {
            int4 idx = reinterpret_cast<const int4*>(ia)[i];
            r.x = va[idx.x]; r.y = va[idx.y]; r.z = va[idx.z]; r.w = va[idx.w];
        } else {
            int4 idx = reinterpret_cast<const int4*>(ib)[i - half4];
            r.x = vb[idx.x]; r.y = vb[idx.y]; r.z = vb[idx.z]; r.w = vb[idx.w];
        }
        reinterpret_cast<float4*>(table)[i] = r;
    }
}

// Pass 2: per neuron, 8 gathers from the table + weighted sum + tanh.
__global__ __launch_bounds__(256) void neuron_kernel(
    const int*   __restrict__ cidx,
    const float* __restrict__ table,
    const float* __restrict__ w,
    float* __restrict__ out)
{
    __shared__ float ws[8];
    if (threadIdx.x < 8) ws[threadIdx.x] = w[threadIdx.x];
    __syncthreads();
    const float w0 = ws[0], w1 = ws[1], w2 = ws[2], w3 = ws[3];
    const float w4 = ws[4], w5 = ws[5], w6 = ws[6], w7 = ws[7];

    const int stride = gridDim.x * blockDim.x;
    for (int n = blockIdx.x * blockDim.x + threadIdx.x; n < NN; n += stride) {
        const int4* p = reinterpret_cast<const int4*>(cidx) + (size_t)n * 2;
        int4 c0 = p[0];
        int4 c1 = p[1];
        float acc = table[c0.x] * w0 + table[c0.y] * w1
                  + table[c0.z] * w2 + table[c0.w] * w3
                  + table[c1.x] * w4 + table[c1.y] * w5
                  + table[c1.z] * w6 + table[c1.w] * w7;
        out[n] = tanhf(acc);
    }
}

// Fallback (ws too small): fused double-gather.
__global__ __launch_bounds__(256) void fused_kernel(
    const float* __restrict__ va, const float* __restrict__ vb,
    const int*   __restrict__ ia, const int*   __restrict__ ib,
    const int*   __restrict__ cidx,
    const float* __restrict__ w,
    float* __restrict__ out)
{
    __shared__ float ws[8];
    if (threadIdx.x < 8) ws[threadIdx.x] = w[threadIdx.x];
    __syncthreads();

    const int stride = gridDim.x * blockDim.x;
    for (int n = blockIdx.x * blockDim.x + threadIdx.x; n < NN; n += stride) {
        const int4* p = reinterpret_cast<const int4*>(cidx) + (size_t)n * 2;
        int4 c0 = p[0];
        int4 c1 = p[1];
        int c[8] = {c0.x, c0.y, c0.z, c0.w, c1.x, c1.y, c1.z, c1.w};
        float acc = 0.f;
        #pragma unroll
        for (int k = 0; k < 8; ++k) {
            int ci = c[k];
            float v = (ci < SRC) ? va[ia[ci]] : vb[ib[ci - SRC]];
            acc += v * ws[k];
        }
        out[n] = tanhf(acc);
    }
}

extern "C" void kernel_launch(void* const* d_in, const int* in_sizes, int n_in,
                              void* d_out, int out_size, void* d_ws, size_t ws_size,
                              hipStream_t stream) {
    const float* va   = (const float*)d_in[0];
    const float* vb   = (const float*)d_in[1];
    const float* w    = (const float*)d_in[2];
    const int*   ia   = (const int*)d_in[3];
    const int*   ib   = (const int*)d_in[4];
    const int*   cidx = (const int*)d_in[5];
    float* out = (float*)d_out;

    const size_t table_bytes = (size_t)(2 * SRC) * sizeof(float);  // 16 MB
    if (ws_size >= table_bytes) {
        float* table = (float*)d_ws;
        build_table_kernel<<<2048, 256, 0, stream>>>(va, vb, ia, ib, table);
        neuron_kernel<<<2048, 256, 0, stream>>>(cidx, table, w, out);
    } else {
        fused_kernel<<<2048, 256, 0, stream>>>(va, vb, ia, ib, cidx, w, out);
    }
}

// Round 3
// 501.602 us; speedup vs baseline: 1.2480x; 1.2480x over previous
//
#include <hip/hip_runtime.h>
#include <hip/hip_fp16.h>

// Problem constants (from reference)
constexpr int SRC = 2000000;      // SRC_SIZE
constexpr int NN  = 4000000;      // NUM_NEURONS
// NUM_WEIGHTS = 8

typedef int v4i __attribute__((ext_vector_type(4)));

// Pass 1: build fp16 table T[i] = values_a[idx_a[i]] (i < SRC) else values_b[idx_b[i-SRC]].
// SRC % 4 == 0, so each 4-chunk is entirely in one half. 4 entries packed into one uint2 store.
__global__ __launch_bounds__(256) void build_table_f16(
    const float* __restrict__ va, const float* __restrict__ vb,
    const int*   __restrict__ ia, const int*   __restrict__ ib,
    __half* __restrict__ table)
{
    const int total4 = (2 * SRC) / 4;  // 1,000,000 chunks
    const int half4  = SRC / 4;        // 500,000
    const int stride = gridDim.x * blockDim.x;
    for (int i = blockIdx.x * blockDim.x + threadIdx.x; i < total4; i += stride) {
        float4 r;
        if (i < half4) {
            int4 idx = reinterpret_cast<const int4*>(ia)[i];
            r.x = va[idx.x]; r.y = va[idx.y]; r.z = va[idx.z]; r.w = va[idx.w];
        } else {
            int4 idx = reinterpret_cast<const int4*>(ib)[i - half4];
            r.x = vb[idx.x]; r.y = vb[idx.y]; r.z = vb[idx.z]; r.w = vb[idx.w];
        }
        unsigned int h0 = __half_as_ushort(__float2half_rn(r.x));
        unsigned int h1 = __half_as_ushort(__float2half_rn(r.y));
        unsigned int h2 = __half_as_ushort(__float2half_rn(r.z));
        unsigned int h3 = __half_as_ushort(__float2half_rn(r.w));
        uint2 p;
        p.x = h0 | (h1 << 16);
        p.y = h2 | (h3 << 16);
        reinterpret_cast<uint2*>(table)[i] = p;
    }
}

// Pass 2: per neuron, 8 fp16 gathers from the table + weighted sum + tanh.
// cidx is streamed non-temporally (zero reuse) so it doesn't evict table lines in L2;
// out likewise stored non-temporally.
__global__ __launch_bounds__(256) void neuron_f16(
    const int*   __restrict__ cidx,
    const __half* __restrict__ table,
    const float* __restrict__ w,
    float* __restrict__ out)
{
    __shared__ float ws[8];
    if (threadIdx.x < 8) ws[threadIdx.x] = w[threadIdx.x];
    __syncthreads();
    const float w0 = ws[0], w1 = ws[1], w2 = ws[2], w3 = ws[3];
    const float w4 = ws[4], w5 = ws[5], w6 = ws[6], w7 = ws[7];

    const int stride = gridDim.x * blockDim.x;
    for (int n = blockIdx.x * blockDim.x + threadIdx.x; n < NN; n += stride) {
        const v4i* p = reinterpret_cast<const v4i*>(cidx) + (size_t)n * 2;
        v4i c0 = __builtin_nontemporal_load(p);
        v4i c1 = __builtin_nontemporal_load(p + 1);
        float acc = __half2float(table[c0.x]) * w0
                  + __half2float(table[c0.y]) * w1
                  + __half2float(table[c0.z]) * w2
                  + __half2float(table[c0.w]) * w3
                  + __half2float(table[c1.x]) * w4
                  + __half2float(table[c1.y]) * w5
                  + __half2float(table[c1.z]) * w6
                  + __half2float(table[c1.w]) * w7;
        __builtin_nontemporal_store(tanhf(acc), &out[n]);
    }
}

// Fallback (ws too small): fused double-gather, full f32.
__global__ __launch_bounds__(256) void fused_kernel(
    const float* __restrict__ va, const float* __restrict__ vb,
    const int*   __restrict__ ia, const int*   __restrict__ ib,
    const int*   __restrict__ cidx,
    const float* __restrict__ w,
    float* __restrict__ out)
{
    __shared__ float ws[8];
    if (threadIdx.x < 8) ws[threadIdx.x] = w[threadIdx.x];
    __syncthreads();

    const int stride = gridDim.x * blockDim.x;
    for (int n = blockIdx.x * blockDim.x + threadIdx.x; n < NN; n += stride) {
        const int4* p = reinterpret_cast<const int4*>(cidx) + (size_t)n * 2;
        int4 c0 = p[0];
        int4 c1 = p[1];
        int c[8] = {c0.x, c0.y, c0.z, c0.w, c1.x, c1.y, c1.z, c1.w};
        float acc = 0.f;
        #pragma unroll
        for (int k = 0; k < 8; ++k) {
            int ci = c[k];
            float v = (ci < SRC) ? va[ia[ci]] : vb[ib[ci - SRC]];
            acc += v * ws[k];
        }
        out[n] = tanhf(acc);
    }
}

extern "C" void kernel_launch(void* const* d_in, const int* in_sizes, int n_in,
                              void* d_out, int out_size, void* d_ws, size_t ws_size,
                              hipStream_t stream) {
    const float* va   = (const float*)d_in[0];
    const float* vb   = (const float*)d_in[1];
    const float* w    = (const float*)d_in[2];
    const int*   ia   = (const int*)d_in[3];
    const int*   ib   = (const int*)d_in[4];
    const int*   cidx = (const int*)d_in[5];
    float* out = (float*)d_out;

    const size_t table_bytes = (size_t)(2 * SRC) * sizeof(__half);  // 8 MB
    if (ws_size >= table_bytes) {
        __half* table = (__half*)d_ws;
        build_table_f16<<<2048, 256, 0, stream>>>(va, vb, ia, ib, table);
        neuron_f16<<<2048, 256, 0, stream>>>(cidx, table, w, out);
    } else {
        fused_kernel<<<2048, 256, 0, stream>>>(va, vb, ia, ib, cidx, w, out);
    }
}

// Round 4
// 427.530 us; speedup vs baseline: 1.4642x; 1.1733x over previous
//
#include <hip/hip_runtime.h>
#include <hip/hip_fp16.h>

// Problem constants (from reference)
constexpr int SRC = 2000000;      // SRC_SIZE
constexpr int NN  = 4000000;      // NUM_NEURONS
constexpr int TBL = 2 * SRC;      // table entries (4M, fp16 -> 8 MB)
constexpr int HALF_TBL = TBL / 2; // 2M entries = 4 MB = one XCD L2
// NUM_WEIGHTS = 8

typedef int v4i __attribute__((ext_vector_type(4)));

// Build stage, chunked by SOURCE-VALUE range so the gather working set
// (one 4 MB half of v) stays L2-resident. Predicated: only entries whose
// index falls in [lo,hi) are gathered/written this sub-pass.
__global__ __launch_bounds__(256) void build_chunk(
    const float* __restrict__ v, const int* __restrict__ idx,
    __half* __restrict__ tout, int lo, int hi)
{
    const int stride = gridDim.x * blockDim.x;
    for (int i = blockIdx.x * blockDim.x + threadIdx.x; i < SRC; i += stride) {
        int c = __builtin_nontemporal_load(&idx[i]);
        if (c >= lo && c < hi) {
            tout[i] = __float2half_rn(v[c]);
        }
    }
}

// Neuron stage, chunked by TABLE range. PHASE 0: accumulate terms with
// c < HALF_TBL (table half 0, 4 MB, L2-resident), write f32 partial (NT).
// PHASE 1: read partial, add terms with c >= HALF_TBL (half 1), tanh, store.
// Gathers are under real `if` so out-of-chunk lines are never fetched.
template<int PHASE>
__global__ __launch_bounds__(256) void neuron_pass(
    const int*    __restrict__ cidx,
    const __half* __restrict__ table,
    const float*  __restrict__ w,
    float*        __restrict__ po)   // partial (phase0 out / phase1 in) == d_out
{
    __shared__ float ws[8];
    if (threadIdx.x < 8) ws[threadIdx.x] = w[threadIdx.x];
    __syncthreads();
    const float w0 = ws[0], w1 = ws[1], w2 = ws[2], w3 = ws[3];
    const float w4 = ws[4], w5 = ws[5], w6 = ws[6], w7 = ws[7];

    const int stride = gridDim.x * blockDim.x;
    for (int n = blockIdx.x * blockDim.x + threadIdx.x; n < NN; n += stride) {
        const v4i* p = reinterpret_cast<const v4i*>(cidx) + (size_t)n * 2;
        v4i c0 = __builtin_nontemporal_load(p);
        v4i c1 = __builtin_nontemporal_load(p + 1);

        float acc;
        if (PHASE == 0) acc = 0.0f;
        else            acc = __builtin_nontemporal_load(&po[n]);

        #define TERM(c, wk)                                                  \
            if (PHASE == 0 ? ((c) < HALF_TBL) : ((c) >= HALF_TBL))           \
                acc += __half2float(table[(c)]) * (wk);
        TERM(c0.x, w0) TERM(c0.y, w1) TERM(c0.z, w2) TERM(c0.w, w3)
        TERM(c1.x, w4) TERM(c1.y, w5) TERM(c1.z, w6) TERM(c1.w, w7)
        #undef TERM

        if (PHASE == 0) __builtin_nontemporal_store(acc, &po[n]);
        else            __builtin_nontemporal_store(tanhf(acc), &po[n]);
    }
}

// Fallback (ws too small): fused double-gather, full f32.
__global__ __launch_bounds__(256) void fused_kernel(
    const float* __restrict__ va, const float* __restrict__ vb,
    const int*   __restrict__ ia, const int*   __restrict__ ib,
    const int*   __restrict__ cidx,
    const float* __restrict__ w,
    float* __restrict__ out)
{
    __shared__ float ws[8];
    if (threadIdx.x < 8) ws[threadIdx.x] = w[threadIdx.x];
    __syncthreads();

    const int stride = gridDim.x * blockDim.x;
    for (int n = blockIdx.x * blockDim.x + threadIdx.x; n < NN; n += stride) {
        const int4* p = reinterpret_cast<const int4*>(cidx) + (size_t)n * 2;
        int4 c0 = p[0];
        int4 c1 = p[1];
        int c[8] = {c0.x, c0.y, c0.z, c0.w, c1.x, c1.y, c1.z, c1.w};
        float acc = 0.f;
        #pragma unroll
        for (int k = 0; k < 8; ++k) {
            int ci = c[k];
            float v = (ci < SRC) ? va[ia[ci]] : vb[ib[ci - SRC]];
            acc += v * ws[k];
        }
        out[n] = tanhf(acc);
    }
}

extern "C" void kernel_launch(void* const* d_in, const int* in_sizes, int n_in,
                              void* d_out, int out_size, void* d_ws, size_t ws_size,
                              hipStream_t stream) {
    const float* va   = (const float*)d_in[0];
    const float* vb   = (const float*)d_in[1];
    const float* w    = (const float*)d_in[2];
    const int*   ia   = (const int*)d_in[3];
    const int*   ib   = (const int*)d_in[4];
    const int*   cidx = (const int*)d_in[5];
    float* out = (float*)d_out;

    const size_t table_bytes = (size_t)TBL * sizeof(__half);  // 8 MB
    if (ws_size >= table_bytes) {
        __half* table = (__half*)d_ws;
        const int HS = SRC / 2;  // 1M source-index chunk boundary (4 MB of v)
        build_chunk<<<2048, 256, 0, stream>>>(va, ia, table,        0,  HS);
        build_chunk<<<2048, 256, 0, stream>>>(va, ia, table,       HS, SRC);
        build_chunk<<<2048, 256, 0, stream>>>(vb, ib, table + SRC,  0,  HS);
        build_chunk<<<2048, 256, 0, stream>>>(vb, ib, table + SRC, HS, SRC);
        neuron_pass<0><<<2048, 256, 0, stream>>>(cidx, table, w, out);
        neuron_pass<1><<<2048, 256, 0, stream>>>(cidx, table, w, out);
    } else {
        fused_kernel<<<2048, 256, 0, stream>>>(va, vb, ia, ib, cidx, w, out);
    }
}

// Round 5
// 424.629 us; speedup vs baseline: 1.4743x; 1.0068x over previous
//
#include <hip/hip_runtime.h>
#include <hip/hip_fp16.h>

// Problem constants (from reference)
constexpr int SRC = 2000000;      // SRC_SIZE
constexpr int NN  = 4000000;      // NUM_NEURONS
constexpr int TBL = 2 * SRC;      // table entries (4M, fp16 -> 8 MB)
constexpr int HALF_TBL = TBL / 2; // 2M entries = 4 MB = one XCD L2

typedef int v4i __attribute__((ext_vector_type(4)));

// Build: one branchless pass. Each thread produces 8 consecutive table
// entries (2x int4 index loads, 8 f32 gathers all in flight, one packed
// 16B fp16 store -> full cache lines, no read-modify-write).
__global__ __launch_bounds__(256) void build_all(
    const float* __restrict__ va, const float* __restrict__ vb,
    const int*   __restrict__ ia, const int*   __restrict__ ib,
    __half* __restrict__ table)
{
    const int ngroups = TBL / 8;          // 500,000 groups of 8 entries
    const int agroups = SRC / 8;          // 250,000 groups in the A half
    const int stride  = gridDim.x * blockDim.x;
    for (int i = blockIdx.x * blockDim.x + threadIdx.x; i < ngroups; i += stride) {
        const float* v;
        const int*   id;
        int base;
        if (i < agroups) { v = va; id = ia; base = i * 8; }
        else             { v = vb; id = ib; base = (i - agroups) * 8; }
        v4i ca = __builtin_nontemporal_load(reinterpret_cast<const v4i*>(id + base));
        v4i cb = __builtin_nontemporal_load(reinterpret_cast<const v4i*>(id + base + 4));
        float f0 = v[ca.x], f1 = v[ca.y], f2 = v[ca.z], f3 = v[ca.w];
        float f4 = v[cb.x], f5 = v[cb.y], f6 = v[cb.z], f7 = v[cb.w];
        uint4 o;
        o.x = (unsigned)__half_as_ushort(__float2half_rn(f0))
            | ((unsigned)__half_as_ushort(__float2half_rn(f1)) << 16);
        o.y = (unsigned)__half_as_ushort(__float2half_rn(f2))
            | ((unsigned)__half_as_ushort(__float2half_rn(f3)) << 16);
        o.z = (unsigned)__half_as_ushort(__float2half_rn(f4))
            | ((unsigned)__half_as_ushort(__float2half_rn(f5)) << 16);
        o.w = (unsigned)__half_as_ushort(__float2half_rn(f6))
            | ((unsigned)__half_as_ushort(__float2half_rn(f7)) << 16);
        reinterpret_cast<uint4*>(table)[i] = o;
    }
}

// Neuron stage, two phases for L2 residency of one 4 MB table half each.
// ILP fix: all 8 masked gathers are issued BEFORE any use (loads only in
// the `if` bodies), so one s_waitcnt covers all 8 in-flight requests.
template<int PHASE>
__global__ __launch_bounds__(256) void neuron_pass(
    const int*    __restrict__ cidx,
    const __half* __restrict__ table,
    const float*  __restrict__ w,
    float*        __restrict__ po)   // partial (phase0 out / phase1 in+out) == d_out
{
    float wk[8];
    #pragma unroll
    for (int k = 0; k < 8; ++k) wk[k] = w[k];

    const int stride = gridDim.x * blockDim.x;
    for (int n = blockIdx.x * blockDim.x + threadIdx.x; n < NN; n += stride) {
        const v4i* p = reinterpret_cast<const v4i*>(cidx) + (size_t)n * 2;
        v4i c0 = __builtin_nontemporal_load(p);
        v4i c1 = __builtin_nontemporal_load(p + 1);
        float prev = (PHASE == 0) ? 0.0f : __builtin_nontemporal_load(&po[n]);

        float v0 = 0.f, v1 = 0.f, v2 = 0.f, v3 = 0.f;
        float v4_ = 0.f, v5 = 0.f, v6 = 0.f, v7 = 0.f;
        if (PHASE == 0) {
            if (c0.x <  HALF_TBL) v0  = __half2float(table[c0.x]);
            if (c0.y <  HALF_TBL) v1  = __half2float(table[c0.y]);
            if (c0.z <  HALF_TBL) v2  = __half2float(table[c0.z]);
            if (c0.w <  HALF_TBL) v3  = __half2float(table[c0.w]);
            if (c1.x <  HALF_TBL) v4_ = __half2float(table[c1.x]);
            if (c1.y <  HALF_TBL) v5  = __half2float(table[c1.y]);
            if (c1.z <  HALF_TBL) v6  = __half2float(table[c1.z]);
            if (c1.w <  HALF_TBL) v7  = __half2float(table[c1.w]);
        } else {
            if (c0.x >= HALF_TBL) v0  = __half2float(table[c0.x]);
            if (c0.y >= HALF_TBL) v1  = __half2float(table[c0.y]);
            if (c0.z >= HALF_TBL) v2  = __half2float(table[c0.z]);
            if (c0.w >= HALF_TBL) v3  = __half2float(table[c0.w]);
            if (c1.x >= HALF_TBL) v4_ = __half2float(table[c1.x]);
            if (c1.y >= HALF_TBL) v5  = __half2float(table[c1.y]);
            if (c1.z >= HALF_TBL) v6  = __half2float(table[c1.z]);
            if (c1.w >= HALF_TBL) v7  = __half2float(table[c1.w]);
        }

        float acc = prev
                  + v0  * wk[0] + v1 * wk[1] + v2 * wk[2] + v3 * wk[3]
                  + v4_ * wk[4] + v5 * wk[5] + v6 * wk[6] + v7 * wk[7];

        if (PHASE == 0) __builtin_nontemporal_store(acc, &po[n]);
        else            __builtin_nontemporal_store(tanhf(acc), &po[n]);
    }
}

// Fallback (ws too small): fused double-gather, full f32.
__global__ __launch_bounds__(256) void fused_kernel(
    const float* __restrict__ va, const float* __restrict__ vb,
    const int*   __restrict__ ia, const int*   __restrict__ ib,
    const int*   __restrict__ cidx,
    const float* __restrict__ w,
    float* __restrict__ out)
{
    __shared__ float ws[8];
    if (threadIdx.x < 8) ws[threadIdx.x] = w[threadIdx.x];
    __syncthreads();

    const int stride = gridDim.x * blockDim.x;
    for (int n = blockIdx.x * blockDim.x + threadIdx.x; n < NN; n += stride) {
        const int4* p = reinterpret_cast<const int4*>(cidx) + (size_t)n * 2;
        int4 c0 = p[0];
        int4 c1 = p[1];
        int c[8] = {c0.x, c0.y, c0.z, c0.w, c1.x, c1.y, c1.z, c1.w};
        float acc = 0.f;
        #pragma unroll
        for (int k = 0; k < 8; ++k) {
            int ci = c[k];
            float v = (ci < SRC) ? va[ia[ci]] : vb[ib[ci - SRC]];
            acc += v * ws[k];
        }
        out[n] = tanhf(acc);
    }
}

extern "C" void kernel_launch(void* const* d_in, const int* in_sizes, int n_in,
                              void* d_out, int out_size, void* d_ws, size_t ws_size,
                              hipStream_t stream) {
    const float* va   = (const float*)d_in[0];
    const float* vb   = (const float*)d_in[1];
    const float* w    = (const float*)d_in[2];
    const int*   ia   = (const int*)d_in[3];
    const int*   ib   = (const int*)d_in[4];
    const int*   cidx = (const int*)d_in[5];
    float* out = (float*)d_out;

    const size_t table_bytes = (size_t)TBL * sizeof(__half);  // 8 MB
    if (ws_size >= table_bytes) {
        __half* table = (__half*)d_ws;
        build_all<<<2048, 256, 0, stream>>>(va, vb, ia, ib, table);
        neuron_pass<0><<<2048, 256, 0, stream>>>(cidx, table, w, out);
        neuron_pass<1><<<2048, 256, 0, stream>>>(cidx, table, w, out);
    } else {
        fused_kernel<<<2048, 256, 0, stream>>>(va, vb, ia, ib, cidx, w, out);
    }
}